// Round 6
// baseline (1916.530 us; speedup 1.0000x reference)
//
#include <hip/hip_runtime.h>
#include <hip/hip_bf16.h>
#include <stdint.h>

typedef __bf16 bf16;
typedef __bf16 bf16x8 __attribute__((ext_vector_type(8)));
typedef float f32x16 __attribute__((ext_vector_type(16)));

typedef uint32_t __attribute__((address_space(1))) * gptr_as1;
typedef uint32_t __attribute__((address_space(3))) * lptr_as3;

__device__ __forceinline__ void async16(const void* g, void* l) {
    __builtin_amdgcn_global_load_lds((gptr_as1)(uintptr_t)g,
                                     (lptr_as3)(uintptr_t)l,
                                     16, 0, 0);
}

__device__ __forceinline__ void bar() {
    asm volatile("" ::: "memory");
    __builtin_amdgcn_s_barrier();
    asm volatile("" ::: "memory");
}

// ---------------------------------------------------------------- cvt f32->bf16
__global__ void cvt_f32_bf16_kernel(const float* __restrict__ src,
                                    bf16* __restrict__ dst, int n8) {
    int i = blockIdx.x * blockDim.x + threadIdx.x;
    if (i >= n8) return;
    const float4* s = reinterpret_cast<const float4*>(src);
    float4 a = s[2 * (size_t)i], b = s[2 * (size_t)i + 1];
    bf16x8 v;
    v[0] = (bf16)a.x; v[1] = (bf16)a.y; v[2] = (bf16)a.z; v[3] = (bf16)a.w;
    v[4] = (bf16)b.x; v[5] = (bf16)b.y; v[6] = (bf16)b.z; v[7] = (bf16)b.w;
    *reinterpret_cast<bf16x8*>(dst + (size_t)i * 8) = v;
}

// cvt + 32-row interleave: src row r -> dst row (r/32)*64 + sel*32 + r%32.
// (32-granularity so each 32-col MFMA n-fragment is pure gate or pure value)
__global__ void cvt_ilv_kernel(const float* __restrict__ src,
                               bf16* __restrict__ dst, int n8, int sel) {
    int i = blockIdx.x * blockDim.x + threadIdx.x;
    if (i >= n8) return;
    const int row = i >> 8;          // / 256  (DIN=2048 -> 256 chunks/row)
    const int c = i & 255;
    const int drow = ((row >> 5) << 6) + (sel << 5) + (row & 31);
    const float4* s = reinterpret_cast<const float4*>(src);
    float4 a = s[2 * (size_t)i], b = s[2 * (size_t)i + 1];
    bf16x8 v;
    v[0] = (bf16)a.x; v[1] = (bf16)a.y; v[2] = (bf16)a.z; v[3] = (bf16)a.w;
    v[4] = (bf16)b.x; v[5] = (bf16)b.y; v[6] = (bf16)b.z; v[7] = (bf16)b.w;
    *reinterpret_cast<bf16x8*>(dst + ((size_t)drow * 256 + c) * 8) = v;
}

// ---------------------------------------------------------------- 256^2 8-phase GEMM, 32x32x16 MFMA
// C = A[M,K] * B[N,K]^T. 512 thr / 8 waves (2x4), wave tile 128x64, BK=64.
// R3 schedule (best measured): per K-tile 4 phases, reads 12/4/8/0 same-phase
// consume, stages P1:A-odd(kt+1)->nA, P2:A-even(kt+2)->cA, P3:B-h0(kt+2)->cB,
// P4:B-h1(kt+2)->cB, vmcnt(6) once per tile (0 at NT-2).
// MFMA shape 32x32x16 (4061 FLOP/cyc vs 3378): per wave per tile 32 MFMA
// (4m x 2n frags x 4 kst), same 24 ds_read_b128, acc[4][2] f32x16.
// Frag layout: lane holds row/col (l&31), k bytes kst*32+(l>>5)*16.
// C/D: col=lane&31, row=(reg&3)+8*(reg>>2)+4*(lane>>5)  [m74/m101].
// EPI=0: bf16(gelu(acc*s1)) | EPI=1: f32(acc*s1) | EPI=2: swiglu, 32-col interleave.
template <int EPI, int K>
__global__ __launch_bounds__(512, 1)
void gemm8p(const bf16* __restrict__ A, const bf16* __restrict__ B,
            void* __restrict__ Cout, const float* __restrict__ s1p,
            const float* __restrict__ s2p, int N, int ldh) {
    __shared__ __align__(16) char sm[131072];

    const int tid = threadIdx.x;
    const int w = tid >> 6, l = tid & 63;
    const int wr = w >> 2, wc = w & 3;

    const int gx = gridDim.x;
    const int nwg = gx * (int)gridDim.y;
    const int orig = blockIdx.y * gx + blockIdx.x;
    const int wg = (orig & 7) * (nwg >> 3) + (orig >> 3);
    const int bm = wg / gx, bn = wg % gx;

    constexpr int NT = K / 64;

    f32x16 acc[4][2] = {};

    char* const bufA0 = sm;
    char* const bufB0 = sm + 32768;
    char* const bufA1 = sm + 65536;
    char* const bufB1 = sm + 98304;
    const int arow = bm * 256, brow = bn * 256;

    const int srow_in = l >> 3;
    const int scolb = ((l & 7) ^ srow_in) << 4;
    auto STAGE = [&](char* ldsT, const bf16* g, int grow0, int kt, int r0) {
        const int rr = r0 + w * 8 + srow_in;
        const char* gp = (const char*)(g + (size_t)(grow0 + rr) * K + kt * 64) + scolb;
        async16(gp, ldsT + r0 * 128 + w * 1024);
    };

    const int rlane = l & 31;
    const int khi = (l >> 5) << 4;   // 0 or 16 bytes (k-half within fragment)
    auto FRAG = [&](const char* tb, int row, int kst) -> bf16x8 {
        const int cb = (kst * 32 + khi) ^ ((row & 7) << 4);
        return *reinterpret_cast<const bf16x8*>(tb + row * 128 + cb);
    };

    // ---- prologue: kt0 full (8) -> buf0; kt1 {A-even, B-h0, B-h1} (6) -> buf1
    STAGE(bufB0, B, brow, 0, 0);   STAGE(bufB0, B, brow, 0, 64);
    STAGE(bufB0, B, brow, 0, 128); STAGE(bufB0, B, brow, 0, 192);
    STAGE(bufA0, A, arow, 0, 0);   STAGE(bufA0, A, arow, 0, 128);
    STAGE(bufA0, A, arow, 0, 64);  STAGE(bufA0, A, arow, 0, 192);
    STAGE(bufA1, A, arow, 1, 0);   STAGE(bufA1, A, arow, 1, 128);
    STAGE(bufB1, B, brow, 1, 0);   STAGE(bufB1, B, brow, 1, 64);
    STAGE(bufB1, B, brow, 1, 128); STAGE(bufB1, B, brow, 1, 192);
    asm volatile("s_waitcnt vmcnt(6)" ::: "memory");
    bar();

    char* cA = bufA0; char* cB = bufB0;
    char* nA = bufA1; char* nB = bufB1;

#pragma unroll 1
    for (int kt = 0; kt < NT; ++kt) {
        bf16x8 avl[8], avh[8], bvl[4], bvh[4];
        // ---- P1 (12 reads): avl (m0,m1) + bvl (n0); stage A-odd(kt+1)->nA
#pragma unroll
        for (int m = 0; m < 2; ++m)
#pragma unroll
            for (int kst = 0; kst < 4; ++kst)
                avl[m * 4 + kst] = FRAG(cA, wr * 128 + m * 32 + rlane, kst);
#pragma unroll
        for (int kst = 0; kst < 4; ++kst)
            bvl[kst] = FRAG(cB, wc * 64 + rlane, kst);
        if (kt + 1 < NT) { STAGE(nA, A, arow, kt + 1, 64); STAGE(nA, A, arow, kt + 1, 192); }
        asm volatile("s_waitcnt lgkmcnt(8)" ::: "memory");
        bar();
        asm volatile("s_waitcnt lgkmcnt(0)" ::: "memory");
        __builtin_amdgcn_sched_barrier(0);
        __builtin_amdgcn_s_setprio(1);
#pragma unroll
        for (int m = 0; m < 2; ++m)
#pragma unroll
            for (int kst = 0; kst < 4; ++kst)
                acc[m][0] = __builtin_amdgcn_mfma_f32_32x32x16_bf16(avl[m * 4 + kst], bvl[kst], acc[m][0], 0, 0, 0);
        __builtin_amdgcn_s_setprio(0);
        bar();
        // ---- P2 (4 reads): bvh (n1); stage A-even(kt+2)->cA
#pragma unroll
        for (int kst = 0; kst < 4; ++kst)
            bvh[kst] = FRAG(cB, wc * 64 + 32 + rlane, kst);
        if (kt + 2 < NT) { STAGE(cA, A, arow, kt + 2, 0); STAGE(cA, A, arow, kt + 2, 128); }
        bar();
        asm volatile("s_waitcnt lgkmcnt(0)" ::: "memory");
        __builtin_amdgcn_sched_barrier(0);
        __builtin_amdgcn_s_setprio(1);
#pragma unroll
        for (int m = 0; m < 2; ++m)
#pragma unroll
            for (int kst = 0; kst < 4; ++kst)
                acc[m][1] = __builtin_amdgcn_mfma_f32_32x32x16_bf16(avl[m * 4 + kst], bvh[kst], acc[m][1], 0, 0, 0);
        __builtin_amdgcn_s_setprio(0);
        bar();
        // ---- P3 (8 reads): avh (m2,m3); stage B-h0(kt+2)->cB
#pragma unroll
        for (int m = 0; m < 2; ++m)
#pragma unroll
            for (int kst = 0; kst < 4; ++kst)
                avh[m * 4 + kst] = FRAG(cA, wr * 128 + 64 + m * 32 + rlane, kst);
        if (kt + 2 < NT) { STAGE(cB, B, brow, kt + 2, 0); STAGE(cB, B, brow, kt + 2, 64); }
        bar();
        asm volatile("s_waitcnt lgkmcnt(0)" ::: "memory");
        __builtin_amdgcn_sched_barrier(0);
        __builtin_amdgcn_s_setprio(1);
#pragma unroll
        for (int m = 0; m < 2; ++m)
#pragma unroll
            for (int kst = 0; kst < 4; ++kst)
                acc[2 + m][0] = __builtin_amdgcn_mfma_f32_32x32x16_bf16(avh[m * 4 + kst], bvl[kst], acc[2 + m][0], 0, 0, 0);
        __builtin_amdgcn_s_setprio(0);
        bar();
        // ---- P4 (0 reads): stage B-h1(kt+2)->cB
        if (kt + 2 < NT) { STAGE(cB, B, brow, kt + 2, 128); STAGE(cB, B, brow, kt + 2, 192); }
        bar();
        __builtin_amdgcn_s_setprio(1);
#pragma unroll
        for (int m = 0; m < 2; ++m)
#pragma unroll
            for (int kst = 0; kst < 4; ++kst)
                acc[2 + m][1] = __builtin_amdgcn_mfma_f32_32x32x16_bf16(avh[m * 4 + kst], bvh[kst], acc[2 + m][1], 0, 0, 0);
        __builtin_amdgcn_s_setprio(0);
        if (kt == NT - 2) { asm volatile("s_waitcnt vmcnt(0)" ::: "memory"); }
        else              { asm volatile("s_waitcnt vmcnt(6)" ::: "memory"); }
        bar();
        char* t = cA; cA = nA; nA = t;
        t = cB; cB = nB; nB = t;
    }

    // epilogue: C/D 32x32 layout: col = lane&31, row = (reg&3)+8*(reg>>2)+4*(lane>>5)
    const float s1 = s1p[0];
    const int r0 = bm * 256 + wr * 128 + ((l >> 5) << 2);
    if constexpr (EPI == 2) {
        const float s2 = s2p[0];
        const int hc = bn * 128 + wc * 32 + rlane;
#pragma unroll
        for (int i = 0; i < 4; ++i)
#pragma unroll
            for (int reg = 0; reg < 16; ++reg) {
                const int row = r0 + i * 32 + (reg & 3) + ((reg >> 2) << 3);
                float g = acc[i][0][reg] * s1;
                float v = acc[i][1][reg] * s2;
                float sig = 1.0f / (1.0f + __expf(-g));
                ((bf16*)Cout)[(size_t)row * ldh + hc] = (bf16)(g * sig * v);
            }
    } else {
        const int c0 = bn * 256 + wc * 64 + rlane;
#pragma unroll
        for (int i = 0; i < 4; ++i)
#pragma unroll
            for (int j = 0; j < 2; ++j)
#pragma unroll
                for (int reg = 0; reg < 16; ++reg) {
                    const int row = r0 + i * 32 + (reg & 3) + ((reg >> 2) << 3);
                    float v = acc[i][j][reg] * s1;
                    size_t idx = (size_t)row * N + (c0 + j * 32);
                    if constexpr (EPI == 0) {
                        float g = 0.5f * v * (1.0f + erff(v * 0.70710678118654752f));
                        ((bf16*)Cout)[idx] = (bf16)g;
                    } else {
                        ((float*)Cout)[idx] = v;
                    }
                }
    }
}

// ---------------------------------------------------------------- launch
extern "C" void kernel_launch(void* const* d_in, const int* in_sizes, int n_in,
                              void* d_out, int out_size, void* d_ws, size_t ws_size,
                              hipStream_t stream) {
    constexpr int NTOK = 8192, DIN = 2048, DHID = 8192;

    const float* x  = (const float*)d_in[0];
    const float* W1 = (const float*)d_in[1];
    const float* W2 = (const float*)d_in[2];
    const float* Wh = (const float*)d_in[3];
    const float* W3 = (const float*)d_in[4];
    const float* s1 = (const float*)d_in[5];
    const float* s2 = (const float*)d_in[6];
    const float* sh = (const float*)d_in[7];
    const float* s3 = (const float*)d_in[8];
    float* out = (float*)d_out;

    char* ws = (char*)d_ws;
    size_t off = 0;
    bf16* xb   = (bf16*)(ws + off); off += (size_t)NTOK * DIN * 2;
    bf16* w12b = (bf16*)(ws + off); off += (size_t)2 * DHID * DIN * 2;
    bf16* w3b  = (bf16*)(ws + off); off += (size_t)DIN * DHID * 2;
    bf16* whb  = (bf16*)(ws + off); off += (size_t)DHID * DHID * 2;
    bf16* h1   = (bf16*)(ws + off); off += (size_t)NTOK * DHID * 2;
    bf16* h2   = (bf16*)(ws + off); off += (size_t)NTOK * DHID * 2;
    if (ws_size < off) return;

    auto cvt = [&](const float* s, bf16* d, size_t n) {
        int n8 = (int)(n / 8);
        cvt_f32_bf16_kernel<<<(n8 + 255) / 256, 256, 0, stream>>>(s, d, n8);
    };
    cvt(x,  xb,  (size_t)NTOK * DIN);
    cvt(Wh, whb, (size_t)DHID * DHID);
    cvt(W3, w3b, (size_t)DIN * DHID);
    {
        int n8 = (int)((size_t)DHID * DIN / 8);
        cvt_ilv_kernel<<<(n8 + 255) / 256, 256, 0, stream>>>(W1, w12b, n8, 0);
        cvt_ilv_kernel<<<(n8 + 255) / 256, 256, 0, stream>>>(W2, w12b, n8, 1);
    }

    // GEMM1+2 fused: C[8192, 16384] over interleaved W12, SwiGLU epilogue -> h1
    gemm8p<2, DIN><<<dim3(2 * DHID / 256, NTOK / 256), 512, 0, stream>>>(
        xb, w12b, h1, s1, s2, 2 * DHID, DHID);
    // hidden GEMM + gelu -> h2
    gemm8p<0, DHID><<<dim3(DHID / 256, NTOK / 256), 512, 0, stream>>>(
        h1, whb, h2, sh, sh, DHID, DHID);
    // output GEMM -> out (f32)
    gemm8p<1, DHID><<<dim3(DIN / 256, NTOK / 256), 512, 0, stream>>>(
        h2, w3b, out, s3, s3, DIN, DIN);
}

// Round 7
// 1803.061 us; speedup vs baseline: 1.0629x; 1.0629x over previous
//
#include <hip/hip_runtime.h>
#include <hip/hip_bf16.h>
#include <stdint.h>

typedef __bf16 bf16;
typedef __bf16 bf16x8 __attribute__((ext_vector_type(8)));
typedef float f32x4 __attribute__((ext_vector_type(4)));

typedef uint32_t __attribute__((address_space(1))) * gptr_as1;
typedef uint32_t __attribute__((address_space(3))) * lptr_as3;

__device__ __forceinline__ void async16(const void* g, void* l) {
    __builtin_amdgcn_global_load_lds((gptr_as1)(uintptr_t)g,
                                     (lptr_as3)(uintptr_t)l,
                                     16, 0, 0);
}

__device__ __forceinline__ void bar() {
    asm volatile("" ::: "memory");
    __builtin_amdgcn_s_barrier();
    asm volatile("" ::: "memory");
}

// T19 interleave directive: 2 stage-loads up front, then weave NDS ds_reads
// into the 16-MFMA stream (4 MFMA : NDS/4 DS_READ). Masks per m137:
// MFMA=0x8, VMEM=0x10, DS_READ=0x100.
template <int NDS>
__device__ __forceinline__ void sgb_interleave() {
    __builtin_amdgcn_sched_group_barrier(0x010, 2, 0);
#pragma unroll
    for (int u = 0; u < 4; ++u) {
        __builtin_amdgcn_sched_group_barrier(0x008, 4, 0);
        if constexpr (NDS > 0)
            __builtin_amdgcn_sched_group_barrier(0x100, NDS / 4, 0);
    }
}

// ---------------------------------------------------------------- cvt f32->bf16
__global__ void cvt_f32_bf16_kernel(const float* __restrict__ src,
                                    bf16* __restrict__ dst, int n8) {
    int i = blockIdx.x * blockDim.x + threadIdx.x;
    if (i >= n8) return;
    const float4* s = reinterpret_cast<const float4*>(src);
    float4 a = s[2 * (size_t)i], b = s[2 * (size_t)i + 1];
    bf16x8 v;
    v[0] = (bf16)a.x; v[1] = (bf16)a.y; v[2] = (bf16)a.z; v[3] = (bf16)a.w;
    v[4] = (bf16)b.x; v[5] = (bf16)b.y; v[6] = (bf16)b.z; v[7] = (bf16)b.w;
    *reinterpret_cast<bf16x8*>(dst + (size_t)i * 8) = v;
}

// cvt + 16-row interleave: src row r (of DHID) -> dst row (r/16)*32 + sel*16 + r%16.
__global__ void cvt_ilv_kernel(const float* __restrict__ src,
                               bf16* __restrict__ dst, int n8, int sel) {
    int i = blockIdx.x * blockDim.x + threadIdx.x;
    if (i >= n8) return;
    const int row = i >> 8;          // / 256  (DIN=2048 -> 256 chunks/row)
    const int c = i & 255;
    const int drow = ((row >> 4) << 5) + (sel << 4) + (row & 15);
    const float4* s = reinterpret_cast<const float4*>(src);
    float4 a = s[2 * (size_t)i], b = s[2 * (size_t)i + 1];
    bf16x8 v;
    v[0] = (bf16)a.x; v[1] = (bf16)a.y; v[2] = (bf16)a.z; v[3] = (bf16)a.w;
    v[4] = (bf16)b.x; v[5] = (bf16)b.y; v[6] = (bf16)b.z; v[7] = (bf16)b.w;
    *reinterpret_cast<bf16x8*>(dst + ((size_t)drow * 256 + c) * 8) = v;
}

// ---------------------------------------------------------------- 256^2 GEMM, issue-interleaved pipeline
// C = A[M,K] * B[N,K]^T. 512 thr / 8 waves (2x4), wave tile 128x64, BK=64.
// LDS: 2 dbuf x (A 32KB + B 32KB) = 128KB, 16x16x32 MFMA, swizzle
// lds_byte = row*128 + (colb ^ ((row&7)<<4)) (R3-proven conflict-free).
// READ-AHEAD dataflow (R4): operands read one phase before their MFMA cluster.
//   P1 MFMA(lo,lo)+read bvh(kt);  P2 MFMA(lo,hi)+read avh(kt)
//   P3 MFMA(hi,lo)+read avl(kt+1); P4 MFMA(hi,hi)+read bvl(kt+1)
// Stages: P1 A-odd(kt+1)->nA, P2 A-even(kt+2)->cA, P3 B-h0(kt+2)->cB, P4 B-h1(kt+2)->cB.
// NEW vs R4/R5: no sched_barrier(0); per-phase sched_group_barrier weaves the
// ds_reads into the MFMA issue stalls (reads have no same-phase deps); ks-outer
// MFMA order breaks acc chains; ONE barrier/phase; vmcnt set {8,8,6,8}
// (end-P3 = 6 fixes R4's no-op wait: B-h1(kt+1) has exactly 6 newer loads).
// WAR proof: each stage's target rows are lgkm-consumed by an MFMA >=1 barrier
// earlier (P2->avl@P1, P3->bvh@P2/bvl@P1-landed, P4->bvh@P2, P1->avh@P3(kt-1)).
// EPI=0: bf16(gelu(acc*s1)) | EPI=1: f32(acc*s1) | EPI=2: swiglu, 16-col interleave.
template <int EPI, int K>
__global__ __launch_bounds__(512, 1)
void gemm8p(const bf16* __restrict__ A, const bf16* __restrict__ B,
            void* __restrict__ Cout, const float* __restrict__ s1p,
            const float* __restrict__ s2p, int N, int ldh) {
    __shared__ __align__(16) char sm[131072];

    const int tid = threadIdx.x;
    const int w = tid >> 6, l = tid & 63;
    const int wr = w >> 2, wc = w & 3;

    const int gx = gridDim.x;
    const int nwg = gx * (int)gridDim.y;
    const int orig = blockIdx.y * gx + blockIdx.x;
    const int wg = (orig & 7) * (nwg >> 3) + (orig >> 3);
    const int bm = wg / gx, bn = wg % gx;

    constexpr int NT = K / 64;

    f32x4 acc[8][4] = {};

    char* const bufA0 = sm;
    char* const bufB0 = sm + 32768;
    char* const bufA1 = sm + 65536;
    char* const bufB1 = sm + 98304;
    const int arow = bm * 256, brow = bn * 256;

    const int srow_in = l >> 3;
    const int scolb = ((l & 7) ^ srow_in) << 4;
    auto STAGE = [&](char* ldsT, const bf16* g, int grow0, int kt, int r0) {
        const int rr = r0 + w * 8 + srow_in;
        const char* gp = (const char*)(g + (size_t)(grow0 + rr) * K + kt * 64) + scolb;
        async16(gp, ldsT + r0 * 128 + w * 1024);
    };

    const int rlane = l & 15;
    const int chi = (l >> 4) << 4;
    auto FRAG = [&](const char* tb, int row, int ks) -> bf16x8 {
        const int cb = (ks * 64 + chi) ^ ((row & 7) << 4);
        return *reinterpret_cast<const bf16x8*>(tb + row * 128 + cb);
    };

    // ---- prologue: kt0 full (8) -> buf0; kt1 {A-even, B-h0, B-h1} (6) -> buf1
    STAGE(bufB0, B, brow, 0, 0);   STAGE(bufB0, B, brow, 0, 64);
    STAGE(bufB0, B, brow, 0, 128); STAGE(bufB0, B, brow, 0, 192);
    STAGE(bufA0, A, arow, 0, 0);   STAGE(bufA0, A, arow, 0, 128);
    STAGE(bufA0, A, arow, 0, 64);  STAGE(bufA0, A, arow, 0, 192);
    STAGE(bufA1, A, arow, 1, 0);   STAGE(bufA1, A, arow, 1, 128);
    STAGE(bufB1, B, brow, 1, 0);   STAGE(bufB1, B, brow, 1, 64);
    STAGE(bufB1, B, brow, 1, 128); STAGE(bufB1, B, brow, 1, 192);
    asm volatile("s_waitcnt vmcnt(6)" ::: "memory");
    bar();

    bf16x8 avl[8], avh[8], bvl[4], bvh[4];
    // pre-read kt0's P1 operands (avl, bvl) from buf0
#pragma unroll
    for (int i = 0; i < 4; ++i)
#pragma unroll
        for (int ks = 0; ks < 2; ++ks)
            avl[i * 2 + ks] = FRAG(bufA0, wr * 128 + i * 16 + rlane, ks);
#pragma unroll
    for (int j = 0; j < 2; ++j)
#pragma unroll
        for (int ks = 0; ks < 2; ++ks)
            bvl[j * 2 + ks] = FRAG(bufB0, wc * 64 + j * 16 + rlane, ks);

    char* cA = bufA0; char* cB = bufB0;
    char* nA = bufA1; char* nB = bufB1;

#pragma unroll 1
    for (int kt = 0; kt < NT; ++kt) {
        // ---- P1: stage A-odd(kt+1)->nA; MFMA (lo,lo) woven with read bvh(kt)
        if (kt + 1 < NT) { STAGE(nA, A, arow, kt + 1, 64); STAGE(nA, A, arow, kt + 1, 192); }
        __builtin_amdgcn_s_setprio(1);
#pragma unroll
        for (int ks = 0; ks < 2; ++ks)
#pragma unroll
            for (int i = 0; i < 4; ++i)
#pragma unroll
                for (int j = 0; j < 2; ++j)
                    acc[i][j] = __builtin_amdgcn_mfma_f32_16x16x32_bf16(avl[i * 2 + ks], bvl[j * 2 + ks], acc[i][j], 0, 0, 0);
#pragma unroll
        for (int j = 0; j < 2; ++j)
#pragma unroll
            for (int ks = 0; ks < 2; ++ks)
                bvh[j * 2 + ks] = FRAG(cB, wc * 64 + 32 + j * 16 + rlane, ks);
        __builtin_amdgcn_s_setprio(0);
        sgb_interleave<4>();
        if (kt < NT - 2) { asm volatile("s_waitcnt vmcnt(8)" ::: "memory"); }
        else             { asm volatile("s_waitcnt vmcnt(0)" ::: "memory"); }
        bar();
        // ---- P2: stage A-even(kt+2)->cA; MFMA (lo,hi) woven with read avh(kt)
        if (kt + 2 < NT) { STAGE(cA, A, arow, kt + 2, 0); STAGE(cA, A, arow, kt + 2, 128); }
        __builtin_amdgcn_s_setprio(1);
#pragma unroll
        for (int ks = 0; ks < 2; ++ks)
#pragma unroll
            for (int i = 0; i < 4; ++i)
#pragma unroll
                for (int j = 0; j < 2; ++j)
                    acc[i][2 + j] = __builtin_amdgcn_mfma_f32_16x16x32_bf16(avl[i * 2 + ks], bvh[j * 2 + ks], acc[i][2 + j], 0, 0, 0);
#pragma unroll
        for (int i = 0; i < 4; ++i)
#pragma unroll
            for (int ks = 0; ks < 2; ++ks)
                avh[i * 2 + ks] = FRAG(cA, wr * 128 + 64 + i * 16 + rlane, ks);
        __builtin_amdgcn_s_setprio(0);
        sgb_interleave<8>();
        if (kt < NT - 2) { asm volatile("s_waitcnt vmcnt(8)" ::: "memory"); }
        else             { asm volatile("s_waitcnt vmcnt(0)" ::: "memory"); }
        bar();
        // ---- P3: stage B-h0(kt+2)->cB; MFMA (hi,lo) woven with read avl(kt+1)
        if (kt + 2 < NT) { STAGE(cB, B, brow, kt + 2, 0); STAGE(cB, B, brow, kt + 2, 64); }
        __builtin_amdgcn_s_setprio(1);
#pragma unroll
        for (int ks = 0; ks < 2; ++ks)
#pragma unroll
            for (int i = 0; i < 4; ++i)
#pragma unroll
                for (int j = 0; j < 2; ++j)
                    acc[4 + i][j] = __builtin_amdgcn_mfma_f32_16x16x32_bf16(avh[i * 2 + ks], bvl[j * 2 + ks], acc[4 + i][j], 0, 0, 0);
        if (kt + 1 < NT) {
#pragma unroll
            for (int i = 0; i < 4; ++i)
#pragma unroll
                for (int ks = 0; ks < 2; ++ks)
                    avl[i * 2 + ks] = FRAG(nA, wr * 128 + i * 16 + rlane, ks);
        }
        __builtin_amdgcn_s_setprio(0);
        sgb_interleave<8>();
        if (kt < NT - 2) { asm volatile("s_waitcnt vmcnt(6)" ::: "memory"); }
        else             { asm volatile("s_waitcnt vmcnt(0)" ::: "memory"); }
        bar();
        // ---- P4: stage B-h1(kt+2)->cB; MFMA (hi,hi) woven with read bvl(kt+1)
        if (kt + 2 < NT) { STAGE(cB, B, brow, kt + 2, 128); STAGE(cB, B, brow, kt + 2, 192); }
        __builtin_amdgcn_s_setprio(1);
#pragma unroll
        for (int ks = 0; ks < 2; ++ks)
#pragma unroll
            for (int i = 0; i < 4; ++i)
#pragma unroll
                for (int j = 0; j < 2; ++j)
                    acc[4 + i][2 + j] = __builtin_amdgcn_mfma_f32_16x16x32_bf16(avh[i * 2 + ks], bvh[j * 2 + ks], acc[4 + i][2 + j], 0, 0, 0);
        if (kt + 1 < NT) {
#pragma unroll
            for (int j = 0; j < 2; ++j)
#pragma unroll
                for (int ks = 0; ks < 2; ++ks)
                    bvl[j * 2 + ks] = FRAG(nB, wc * 64 + j * 16 + rlane, ks);
        }
        __builtin_amdgcn_s_setprio(0);
        sgb_interleave<4>();
        if (kt < NT - 2) { asm volatile("s_waitcnt vmcnt(8)" ::: "memory"); }
        else             { asm volatile("s_waitcnt vmcnt(0)" ::: "memory"); }
        bar();
        char* t = cA; cA = nA; nA = t;
        t = cB; cB = nB; nB = t;
    }

    const float s1 = s1p[0];
    const int r0 = bm * 256 + wr * 128 + ((l >> 4) << 2);
    if constexpr (EPI == 2) {
        const float s2 = s2p[0];
        const int hcb = (bn * 8 + wc * 2) * 16 + rlane;
#pragma unroll
        for (int i = 0; i < 8; ++i)
#pragma unroll
            for (int jp = 0; jp < 2; ++jp)
#pragma unroll
                for (int q = 0; q < 4; ++q) {
                    float g = acc[i][2 * jp][q] * s1;
                    float v = acc[i][2 * jp + 1][q] * s2;
                    float sig = 1.0f / (1.0f + __expf(-g));
                    ((bf16*)Cout)[(size_t)(r0 + i * 16 + q) * ldh + hcb + jp * 16] =
                        (bf16)(g * sig * v);
                }
    } else {
        const int c0 = bn * 256 + wc * 64 + rlane;
#pragma unroll
        for (int i = 0; i < 8; ++i)
#pragma unroll
            for (int j = 0; j < 4; ++j)
#pragma unroll
                for (int q = 0; q < 4; ++q) {
                    float v = acc[i][j][q] * s1;
                    size_t idx = (size_t)(r0 + i * 16 + q) * N + (c0 + j * 16);
                    if constexpr (EPI == 0) {
                        float g = 0.5f * v * (1.0f + erff(v * 0.70710678118654752f));
                        ((bf16*)Cout)[idx] = (bf16)g;
                    } else {
                        ((float*)Cout)[idx] = v;
                    }
                }
    }
}

// ---------------------------------------------------------------- launch
extern "C" void kernel_launch(void* const* d_in, const int* in_sizes, int n_in,
                              void* d_out, int out_size, void* d_ws, size_t ws_size,
                              hipStream_t stream) {
    constexpr int NTOK = 8192, DIN = 2048, DHID = 8192;

    const float* x  = (const float*)d_in[0];
    const float* W1 = (const float*)d_in[1];
    const float* W2 = (const float*)d_in[2];
    const float* Wh = (const float*)d_in[3];
    const float* W3 = (const float*)d_in[4];
    const float* s1 = (const float*)d_in[5];
    const float* s2 = (const float*)d_in[6];
    const float* sh = (const float*)d_in[7];
    const float* s3 = (const float*)d_in[8];
    float* out = (float*)d_out;

    char* ws = (char*)d_ws;
    size_t off = 0;
    bf16* xb   = (bf16*)(ws + off); off += (size_t)NTOK * DIN * 2;
    bf16* w12b = (bf16*)(ws + off); off += (size_t)2 * DHID * DIN * 2;
    bf16* w3b  = (bf16*)(ws + off); off += (size_t)DIN * DHID * 2;
    bf16* whb  = (bf16*)(ws + off); off += (size_t)DHID * DHID * 2;
    bf16* h1   = (bf16*)(ws + off); off += (size_t)NTOK * DHID * 2;
    bf16* h2   = (bf16*)(ws + off); off += (size_t)NTOK * DHID * 2;
    if (ws_size < off) return;

    auto cvt = [&](const float* s, bf16* d, size_t n) {
        int n8 = (int)(n / 8);
        cvt_f32_bf16_kernel<<<(n8 + 255) / 256, 256, 0, stream>>>(s, d, n8);
    };
    cvt(x,  xb,  (size_t)NTOK * DIN);
    cvt(Wh, whb, (size_t)DHID * DHID);
    cvt(W3, w3b, (size_t)DIN * DHID);
    {
        int n8 = (int)((size_t)DHID * DIN / 8);
        cvt_ilv_kernel<<<(n8 + 255) / 256, 256, 0, stream>>>(W1, w12b, n8, 0);
        cvt_ilv_kernel<<<(n8 + 255) / 256, 256, 0, stream>>>(W2, w12b, n8, 1);
    }

    // GEMM1+2 fused: C[8192, 16384] over interleaved W12, SwiGLU epilogue -> h1
    gemm8p<2, DIN><<<dim3(2 * DHID / 256, NTOK / 256), 512, 0, stream>>>(
        xb, w12b, h1, s1, s2, 2 * DHID, DHID);
    // hidden GEMM + gelu -> h2
    gemm8p<0, DHID><<<dim3(DHID / 256, NTOK / 256), 512, 0, stream>>>(
        h1, whb, h2, sh, sh, DHID, DHID);
    // output GEMM -> out (f32)
    gemm8p<1, DHID><<<dim3(DIN / 256, NTOK / 256), 512, 0, stream>>>(
        h2, w3b, out, s3, s3, DIN, DIN);
}